// Round 1
// 269.451 us; speedup vs baseline: 1.0621x; 1.0621x over previous
//
#include <hip/hip_runtime.h>
#include <hip/hip_fp16.h>

#define DIM 128
#define KCODES 1024
#define BROWS 64          // rows per block (4 waves x 16 rows)
#define NCHUNK 64         // codes per LDS chunk (double-buffered)
#define NCHUNKS (KCODES / NCHUNK)
#define TAU_ACC 1.2e-3f   // acc units (= dot - ||e||^2/2); fp16 2-pass err ~8e-5 rms -> ~10 sigma

typedef _Float16 f16x8 __attribute__((ext_vector_type(8)));
typedef float f32x4 __attribute__((ext_vector_type(4)));

__device__ __forceinline__ void gl_lds16(const void* g, void* l) {
    __builtin_amdgcn_global_load_lds(
        (const __attribute__((address_space(1))) void*)g,
        (__attribute__((address_space(3))) void*)l, 16, 0, 0);
}

// ---------- prep A: ||e_k||^2 (arithmetic identical to previous passing kernel;
// the exact-refine path depends on these exact roundings) ----------
__global__ void enorm_kernel(const float* __restrict__ embed, float* __restrict__ enorm) {
    int k = blockIdx.x * blockDim.x + threadIdx.x;
    if (k < KCODES) {
        const float4* row = (const float4*)(embed + (size_t)k * DIM);
        float s = 0.f;
#pragma unroll
        for (int d = 0; d < DIM / 4; ++d) {
            float4 v = row[d];
            s = fmaf(v.x, v.x, s); s = fmaf(v.y, v.y, s);
            s = fmaf(v.z, v.z, s); s = fmaf(v.w, v.w, s);
        }
        enorm[k] = s;
    }
}

// ---------- prep B: E -> fp16 (hi only), XOR-swizzled 16B-segment layout ----------
// Segment = 8 halfs (16 B). Row k's logical segment s stored at s ^ (k & 15).
// Staging copies lane-linearly (global_load_lds friendly); the MFMA B-read
// deswizzles with (ks*4+q)^n -> conflict-free (measured 0 previously).
__global__ void pack_kernel(const float* __restrict__ embed, _Float16* __restrict__ Eh) {
    int t = blockIdx.x * blockDim.x + threadIdx.x;   // 0 .. KCODES*16-1
    int k = t >> 4;
    int s = t & 15;
    const float* src = embed + (size_t)k * DIM + s * 8;
    float4 a0 = *(const float4*)src;
    float4 a1 = *(const float4*)(src + 4);
    float f[8] = {a0.x, a0.y, a0.z, a0.w, a1.x, a1.y, a1.z, a1.w};
    f16x8 h8;
#pragma unroll
    for (int j = 0; j < 8; ++j) h8[j] = (_Float16)f[j];
    *(f16x8*)&Eh[(size_t)k * DIM + (size_t)((s ^ (k & 15)) * 8)] = h8;
}

// ---------- main: fp16 2-pass MFMA argmax, 1-barrier double-buffered pipeline ----------
__global__ __launch_bounds__(256, 4)
void argmax_mfma_kernel(const float* __restrict__ x, const float* __restrict__ embed,
                        const _Float16* __restrict__ Eh, const float* __restrict__ enorm,
                        float* __restrict__ outq, float* __restrict__ outi) {
    __shared__ __align__(16) _Float16 ebuf[2][NCHUNK * DIM];  // 2 x 16 KB
    __shared__ float enorm_l[KCODES];                          // 4 KB: -0.5*||e||^2
    __shared__ int idx_l[BROWS];
    __shared__ int flist[BROWS];
    __shared__ int fcnt;

    const int tid  = threadIdx.x;
    const int w    = tid >> 6;       // wave 0..3
    const int lane = tid & 63;
    const int n    = lane & 15;      // code col class / A row
    const int q    = lane >> 4;      // k-segment (A/B) / row group (C)
    const size_t row0 = (size_t)blockIdx.x * BROWS;

    if (tid == 0) fcnt = 0;
    {   // enorm -> LDS as -0.5*||e||^2 (folded into MFMA C-init)
        float4 e4 = ((const float4*)enorm)[tid];
        float4 v; v.x = -0.5f * e4.x; v.y = -0.5f * e4.y; v.z = -0.5f * e4.z; v.w = -0.5f * e4.w;
        ((float4*)enorm_l)[tid] = v;
    }

    // issue chunk 0 staging straight to LDS (lands during A-conversion below)
#pragma unroll
    for (int j = 0; j < 4; ++j)
        gl_lds16(Eh + (size_t)(tid + j * 256) * 8, &ebuf[0][(size_t)(w * 64 + j * 256) * 8]);

    // A fragments: wave's 16 rows as fp16 hi/lo splits, resident whole loop.
    // layout: A[m=lane&15][k = ks*32 + q*8 + j]  (same geometry as bf16, verified prev session)
    f16x8 xh[4], xl[4];
#pragma unroll
    for (int ks = 0; ks < 4; ++ks) {
        const float* xp = x + (row0 + (size_t)(w * 16 + n)) * DIM + ks * 32 + q * 8;
        float4 a0 = *(const float4*)xp;
        float4 a1 = *(const float4*)(xp + 4);
        float f[8] = {a0.x, a0.y, a0.z, a0.w, a1.x, a1.y, a1.z, a1.w};
        f16x8 h, l;
#pragma unroll
        for (int j = 0; j < 8; ++j) {
            _Float16 hh = (_Float16)f[j];
            h[j] = hh;
            l[j] = (_Float16)(f[j] - (float)hh);
        }
        xh[ks] = h; xl[ks] = l;
    }

    float best[4], sec[4]; int bidx[4];
#pragma unroll
    for (int rg = 0; rg < 4; ++rg) { best[rg] = -3.4e38f; sec[rg] = -3.4e38f; bidx[rg] = 0; }

    int curb = 0;
    for (int kt = 0; kt < NCHUNKS; ++kt) {
        // Barrier drains each wave's own gl_lds for chunk kt (issued a full compute
        // phase ago -> ~free) and orders prev-chunk reads before the buffer is reused.
        __syncthreads();
        if (kt + 1 < NCHUNKS) {
            const _Float16* gs = Eh + (size_t)(kt + 1) * NCHUNK * DIM;
            _Float16* lb = ebuf[curb ^ 1];
#pragma unroll
            for (int j = 0; j < 4; ++j)
                gl_lds16(gs + (size_t)(tid + j * 256) * 8, lb + (size_t)(w * 64 + j * 256) * 8);
        }

        const _Float16* eb = ebuf[curb];
        const int c0 = kt * NCHUNK;
        f32x4 acc[4];
#pragma unroll
        for (int ns = 0; ns < 4; ++ns) {
            float e = enorm_l[c0 + ns * 16 + n];   // broadcast across quads: conflict-free
            f32x4 a; a[0] = e; a[1] = e; a[2] = e; a[3] = e;
            acc[ns] = a;
        }
#pragma unroll
        for (int ks = 0; ks < 4; ++ks) {
            f16x8 bh[4];
#pragma unroll
            for (int ns = 0; ns < 4; ++ns)
                bh[ns] = *(const f16x8*)&eb[(ns * 16 + n) * DIM + (((ks * 4 + q) ^ n) * 8)];
#pragma unroll
            for (int ns = 0; ns < 4; ++ns)
                acc[ns] = __builtin_amdgcn_mfma_f32_16x16x32_f16(xh[ks], bh[ns], acc[ns], 0, 0, 0);
#pragma unroll
            for (int ns = 0; ns < 4; ++ns)
                acc[ns] = __builtin_amdgcn_mfma_f32_16x16x32_f16(xl[ks], bh[ns], acc[ns], 0, 0, 0);
        }
#pragma unroll
        for (int ns = 0; ns < 4; ++ns) {
            int code = c0 + ns * 16 + n;
#pragma unroll
            for (int rg = 0; rg < 4; ++rg) {
                float sc = acc[ns][rg];          // = x.e - ||e||^2/2  (acc units)
                if (sc > best[rg]) { sec[rg] = best[rg]; best[rg] = sc; bidx[rg] = code; }
                else if (sc > sec[rg]) sec[rg] = sc;
            }
        }
        curb ^= 1;
    }

    // reduce top-2 across the 16 col classes (lane bits 0..3)
#pragma unroll
    for (int mask = 1; mask < 16; mask <<= 1) {
#pragma unroll
        for (int rg = 0; rg < 4; ++rg) {
            float ob = __shfl_xor(best[rg], mask);
            float os = __shfl_xor(sec[rg], mask);
            int   oi = __shfl_xor(bidx[rg], mask);
            if (ob > best[rg] || (ob == best[rg] && oi < bidx[rg])) {
                sec[rg] = fmaxf(best[rg], os);
                best[rg] = ob; bidx[rg] = oi;
            } else {
                sec[rg] = fmaxf(sec[rg], ob);
            }
        }
    }
    if (n == 0) {
#pragma unroll
        for (int rg = 0; rg < 4; ++rg) {
            int r = w * 16 + q * 4 + rg;
            idx_l[r] = bidx[rg];
            if (best[rg] - sec[rg] < TAU_ACC) {
                int p = atomicAdd(&fcnt, 1);
                flist[p] = r;
            }
        }
    }
    __syncthreads();

    // exact fp32 refine for near-tie rows (arithmetic identical to passing kernel)
    int nf = fcnt;
    for (int f = w; f < nf; f += 4) {
        int r = flist[f];
        const float4* xg4 = (const float4*)(x + (row0 + r) * DIM);
        float b = -3.4e38f; int bi = 0;
        for (int c = lane * 16; c < lane * 16 + 16; ++c) {
            const float4* eg4 = (const float4*)(embed + (size_t)c * DIM);
            float s = 0.f;
#pragma unroll 8
            for (int d = 0; d < DIM / 4; ++d) {
                float4 xv = xg4[d], ev = eg4[d];
                s = fmaf(xv.x, ev.x, s); s = fmaf(xv.y, ev.y, s);
                s = fmaf(xv.z, ev.z, s); s = fmaf(xv.w, ev.w, s);
            }
            float sc = fmaf(2.f, s, -enorm[c]);
            if (sc > b) { b = sc; bi = c; }
        }
#pragma unroll
        for (int mask = 1; mask < 64; mask <<= 1) {
            float ob = __shfl_xor(b, mask);
            int   oi = __shfl_xor(bi, mask);
            if (ob > b || (ob == b && oi < bi)) { b = ob; bi = oi; }
        }
        if (lane == 0) idx_l[r] = bi;
    }
    __syncthreads();

    // fused gather (embed L2-resident) + float index write
    const float4* e4 = (const float4*)embed;
    float4* oq4 = (float4*)outq + row0 * (DIM / 4);
#pragma unroll
    for (int i = 0; i < 8; ++i) {
        int g = tid + i * 256;
        int r = g >> 5, d4 = g & 31;
        int id = idx_l[r];
        oq4[g] = e4[(size_t)id * (DIM / 4) + d4];
    }
    if (tid < BROWS) outi[row0 + tid] = (float)idx_l[tid];
}

extern "C" void kernel_launch(void* const* d_in, const int* in_sizes, int n_in,
                              void* d_out, int out_size, void* d_ws, size_t ws_size,
                              hipStream_t stream) {
    const float* x     = (const float*)d_in[0];
    const float* embed = (const float*)d_in[1];
    const int x_elems  = in_sizes[0];          // 12,288,000
    const int n_rows   = x_elems / DIM;        // 96,000

    float*    enorm = (float*)d_ws;                              // 4 KB
    _Float16* Eh    = (_Float16*)((char*)d_ws + 4096);           // 256 KB

    float* outq = (float*)d_out;
    float* outi = (float*)d_out + (size_t)x_elems;

    enorm_kernel<<<KCODES / 256, 256, 0, stream>>>(embed, enorm);
    pack_kernel<<<KCODES * 16 / 256, 256, 0, stream>>>(embed, Eh);
    argmax_mfma_kernel<<<n_rows / BROWS, 256, 0, stream>>>(x, embed, Eh, enorm, outq, outi);
}

// Round 2
// 261.773 us; speedup vs baseline: 1.0932x; 1.0293x over previous
//
#include <hip/hip_runtime.h>
#include <hip/hip_fp16.h>

#define DIM 128
#define KCODES 1024
#define BROWS 128         // rows per block = 4 waves x 32 rows
#define NCH (KCODES / 16) // 64 chunks of 16 codes
#define TAU_ACC 1.2e-3f   // acc units (= x.e - ||e||^2/2); fp16 2-pass err ~1.6e-4 rms

typedef _Float16 f16x8 __attribute__((ext_vector_type(8)));
typedef float f32x4 __attribute__((ext_vector_type(4)));

struct B4 { f16x8 b0, b1, b2, b3; };

// B fragment for chunk c (16 codes), all 4 k-slices, fully coalesced:
// seg index = c*256 + ks*64 + lane  ->  halfs at seg*8
__device__ __forceinline__ B4 loadB(const _Float16* __restrict__ Ehp, int c, int lane) {
    const _Float16* p = Ehp + (size_t)c * 2048 + (size_t)lane * 8;
    B4 r;
    r.b0 = *(const f16x8*)(p);
    r.b1 = *(const f16x8*)(p + 512);
    r.b2 = *(const f16x8*)(p + 1024);
    r.b3 = *(const f16x8*)(p + 1536);
    return r;
}

// ---------- prep A: ||e_k||^2 (identical arithmetic to passing kernel) ----------
__global__ void enorm_kernel(const float* __restrict__ embed, float* __restrict__ enorm) {
    int k = blockIdx.x * blockDim.x + threadIdx.x;
    if (k < KCODES) {
        const float4* row = (const float4*)(embed + (size_t)k * DIM);
        float s = 0.f;
#pragma unroll
        for (int d = 0; d < DIM / 4; ++d) {
            float4 v = row[d];
            s = fmaf(v.x, v.x, s); s = fmaf(v.y, v.y, s);
            s = fmaf(v.z, v.z, s); s = fmaf(v.w, v.w, s);
        }
        enorm[k] = s;
    }
}

// ---------- prep B: E -> fp16, MFMA-fragment-ordered coalesced layout ----------
// t = c*256 + ks*64 + q*16 + n  (dst seg == t):
//   Ehp[t*8 + j] = (f16) embed[c*16 + n][ks*32 + q*8 + j]
__global__ void pack_kernel(const float* __restrict__ embed, _Float16* __restrict__ Ehp) {
    int t = blockIdx.x * blockDim.x + threadIdx.x;   // 0 .. KCODES*16-1
    int n  = t & 15;
    int q  = (t >> 4) & 3;
    int ks = (t >> 6) & 3;
    int c  = t >> 8;
    const float* src = embed + (size_t)(c * 16 + n) * DIM + ks * 32 + q * 8;
    float4 a0 = *(const float4*)src;
    float4 a1 = *(const float4*)(src + 4);
    float f[8] = {a0.x, a0.y, a0.z, a0.w, a1.x, a1.y, a1.z, a1.w};
    f16x8 h8;
#pragma unroll
    for (int j = 0; j < 8; ++j) h8[j] = (_Float16)f[j];
    *(f16x8*)&Ehp[(size_t)t * 8] = h8;
}

// ---------- main: register-streamed fp16 2-pass MFMA argmax, no LDS staging ----------
__global__ __launch_bounds__(256, 3)
void argmax_mfma_kernel(const float* __restrict__ x, const float* __restrict__ embed,
                        const _Float16* __restrict__ Ehp, const float* __restrict__ enorm,
                        float* __restrict__ outq, float* __restrict__ outi) {
    __shared__ float enorm_l[KCODES];   // -0.5*||e||^2
    __shared__ int idx_l[BROWS];
    __shared__ int flist[BROWS];
    __shared__ int fcnt;

    const int tid  = threadIdx.x;
    const int w    = tid >> 6;       // wave 0..3
    const int lane = tid & 63;
    const int n    = lane & 15;      // code col / A row class
    const int q    = lane >> 4;      // k-segment (A/B) / C row group
    const size_t row0 = (size_t)blockIdx.x * BROWS;

    if (tid == 0) fcnt = 0;
    {   // enorm -> LDS as -0.5*||e||^2 (folded into MFMA C-init)
        float4 e4 = ((const float4*)enorm)[tid];
        float4 v; v.x = -0.5f * e4.x; v.y = -0.5f * e4.y; v.z = -0.5f * e4.z; v.w = -0.5f * e4.w;
        ((float4*)enorm_l)[tid] = v;
    }

    // A fragments: this wave's 32 rows (2 rowsets of 16), fp16 hi/lo split.
    // layout: A[m = lane&15][k = ks*32 + q*8 + j]  (geometry verified, passing)
    f16x8 xh[2][4], xl[2][4];
#pragma unroll
    for (int s = 0; s < 2; ++s)
#pragma unroll
        for (int ks = 0; ks < 4; ++ks) {
            const float* xp = x + (row0 + (size_t)(w * 32 + s * 16 + n)) * DIM + ks * 32 + q * 8;
            float4 a0 = *(const float4*)xp;
            float4 a1 = *(const float4*)(xp + 4);
            float f[8] = {a0.x, a0.y, a0.z, a0.w, a1.x, a1.y, a1.z, a1.w};
            f16x8 h, l;
#pragma unroll
            for (int j = 0; j < 8; ++j) {
                _Float16 hh = (_Float16)f[j];
                h[j] = hh;
                l[j] = (_Float16)(f[j] - (float)hh);
            }
            xh[s][ks] = h; xl[s][ks] = l;
        }

    __syncthreads();   // enorm_l ready

    float best[2][4], sec[2][4]; int bidx[2][4];
#pragma unroll
    for (int s = 0; s < 2; ++s)
#pragma unroll
        for (int rg = 0; rg < 4; ++rg) { best[s][rg] = -3.4e38f; sec[s][rg] = -3.4e38f; bidx[s][rg] = 0; }

    B4 bcur = loadB(Ehp, 0, lane);

    for (int c = 0; c < NCH; ++c) {
        B4 bnext = loadB(Ehp, (c + 1) & (NCH - 1), lane);  // prefetch distance 1
        float e = enorm_l[c * 16 + n];                      // broadcast, conflict-free
        f32x4 acc0 = {e, e, e, e};
        f32x4 acc1 = {e, e, e, e};
        // two independent 8-deep chains (rowset 0 / rowset 1)
        acc0 = __builtin_amdgcn_mfma_f32_16x16x32_f16(xh[0][0], bcur.b0, acc0, 0, 0, 0);
        acc1 = __builtin_amdgcn_mfma_f32_16x16x32_f16(xh[1][0], bcur.b0, acc1, 0, 0, 0);
        acc0 = __builtin_amdgcn_mfma_f32_16x16x32_f16(xh[0][1], bcur.b1, acc0, 0, 0, 0);
        acc1 = __builtin_amdgcn_mfma_f32_16x16x32_f16(xh[1][1], bcur.b1, acc1, 0, 0, 0);
        acc0 = __builtin_amdgcn_mfma_f32_16x16x32_f16(xh[0][2], bcur.b2, acc0, 0, 0, 0);
        acc1 = __builtin_amdgcn_mfma_f32_16x16x32_f16(xh[1][2], bcur.b2, acc1, 0, 0, 0);
        acc0 = __builtin_amdgcn_mfma_f32_16x16x32_f16(xh[0][3], bcur.b3, acc0, 0, 0, 0);
        acc1 = __builtin_amdgcn_mfma_f32_16x16x32_f16(xh[1][3], bcur.b3, acc1, 0, 0, 0);
        acc0 = __builtin_amdgcn_mfma_f32_16x16x32_f16(xl[0][0], bcur.b0, acc0, 0, 0, 0);
        acc1 = __builtin_amdgcn_mfma_f32_16x16x32_f16(xl[1][0], bcur.b0, acc1, 0, 0, 0);
        acc0 = __builtin_amdgcn_mfma_f32_16x16x32_f16(xl[0][1], bcur.b1, acc0, 0, 0, 0);
        acc1 = __builtin_amdgcn_mfma_f32_16x16x32_f16(xl[1][1], bcur.b1, acc1, 0, 0, 0);
        acc0 = __builtin_amdgcn_mfma_f32_16x16x32_f16(xl[0][2], bcur.b2, acc0, 0, 0, 0);
        acc1 = __builtin_amdgcn_mfma_f32_16x16x32_f16(xl[1][2], bcur.b2, acc1, 0, 0, 0);
        acc0 = __builtin_amdgcn_mfma_f32_16x16x32_f16(xl[0][3], bcur.b3, acc0, 0, 0, 0);
        acc1 = __builtin_amdgcn_mfma_f32_16x16x32_f16(xl[1][3], bcur.b3, acc1, 0, 0, 0);

        int code = c * 16 + n;
#pragma unroll
        for (int rg = 0; rg < 4; ++rg) {
            float sc0 = acc0[rg];
            sec[0][rg]  = __builtin_amdgcn_fmed3f(best[0][rg], sec[0][rg], sc0);
            bidx[0][rg] = (sc0 > best[0][rg]) ? code : bidx[0][rg];
            best[0][rg] = fmaxf(best[0][rg], sc0);
            float sc1 = acc1[rg];
            sec[1][rg]  = __builtin_amdgcn_fmed3f(best[1][rg], sec[1][rg], sc1);
            bidx[1][rg] = (sc1 > best[1][rg]) ? code : bidx[1][rg];
            best[1][rg] = fmaxf(best[1][rg], sc1);
        }
        bcur = bnext;
        if ((c & 15) == 15 && c + 1 < NCH) __syncthreads();  // keep waves in step for L1 sharing
    }

    // reduce top-2 across the 16 col classes (lane bits 0..3)
#pragma unroll
    for (int mask = 1; mask < 16; mask <<= 1) {
#pragma unroll
        for (int s = 0; s < 2; ++s)
#pragma unroll
            for (int rg = 0; rg < 4; ++rg) {
                float ob = __shfl_xor(best[s][rg], mask);
                float os = __shfl_xor(sec[s][rg], mask);
                int   oi = __shfl_xor(bidx[s][rg], mask);
                if (ob > best[s][rg] || (ob == best[s][rg] && oi < bidx[s][rg])) {
                    sec[s][rg] = fmaxf(best[s][rg], os);
                    best[s][rg] = ob; bidx[s][rg] = oi;
                } else {
                    sec[s][rg] = fmaxf(sec[s][rg], ob);
                }
            }
    }
    if (n == 0) {
#pragma unroll
        for (int s = 0; s < 2; ++s)
#pragma unroll
            for (int rg = 0; rg < 4; ++rg) {
                int r = w * 32 + s * 16 + q * 4 + rg;
                idx_l[r] = bidx[s][rg];
                if (best[s][rg] - sec[s][rg] < TAU_ACC) {
                    int p = atomicAdd(&fcnt, 1);
                    flist[p] = r;
                }
            }
    }
    __syncthreads();

    // exact fp32 refine for near-tie rows (arithmetic identical to passing kernel)
    int nf = fcnt;
    for (int f = w; f < nf; f += 4) {
        int r = flist[f];
        const float4* xg4 = (const float4*)(x + (row0 + r) * DIM);
        float b = -3.4e38f; int bi = 0;
        for (int c = lane * 16; c < lane * 16 + 16; ++c) {
            const float4* eg4 = (const float4*)(embed + (size_t)c * DIM);
            float s = 0.f;
#pragma unroll 8
            for (int d = 0; d < DIM / 4; ++d) {
                float4 xv = xg4[d], ev = eg4[d];
                s = fmaf(xv.x, ev.x, s); s = fmaf(xv.y, ev.y, s);
                s = fmaf(xv.z, ev.z, s); s = fmaf(xv.w, ev.w, s);
            }
            float sc = fmaf(2.f, s, -enorm[c]);
            if (sc > b) { b = sc; bi = c; }
        }
#pragma unroll
        for (int mask = 1; mask < 64; mask <<= 1) {
            float ob = __shfl_xor(b, mask);
            int   oi = __shfl_xor(bi, mask);
            if (ob > b || (ob == b && oi < bi)) { b = ob; bi = oi; }
        }
        if (lane == 0) idx_l[r] = bi;
    }
    __syncthreads();

    // fused gather (embed L2-resident) + float index write
    const float4* e4 = (const float4*)embed;
    float4* oq4 = (float4*)outq + row0 * (DIM / 4);
#pragma unroll
    for (int i = 0; i < 16; ++i) {
        int g = tid + i * 256;
        int r = g >> 5, d4 = g & 31;
        int id = idx_l[r];
        oq4[g] = e4[(size_t)id * (DIM / 4) + d4];
    }
    if (tid < BROWS) outi[row0 + tid] = (float)idx_l[tid];
}

extern "C" void kernel_launch(void* const* d_in, const int* in_sizes, int n_in,
                              void* d_out, int out_size, void* d_ws, size_t ws_size,
                              hipStream_t stream) {
    const float* x     = (const float*)d_in[0];
    const float* embed = (const float*)d_in[1];
    const int x_elems  = in_sizes[0];          // 12,288,000
    const int n_rows   = x_elems / DIM;        // 96,000

    float*    enorm = (float*)d_ws;                              // 4 KB
    _Float16* Ehp   = (_Float16*)((char*)d_ws + 4096);           // 256 KB

    float* outq = (float*)d_out;
    float* outi = (float*)d_out + (size_t)x_elems;

    enorm_kernel<<<KCODES / 256, 256, 0, stream>>>(embed, enorm);
    pack_kernel<<<KCODES * 16 / 256, 256, 0, stream>>>(embed, Ehp);
    argmax_mfma_kernel<<<n_rows / BROWS, 256, 0, stream>>>(x, embed, Ehp, enorm, outq, outi);
}